// Round 1
// baseline (974.170 us; speedup 1.0000x reference)
//
#include <hip/hip_runtime.h>
#include <hip/hip_bf16.h>
#include <cstdint>
#include <cstddef>

// ---------------- CSR build ----------------

__global__ void k_zero_int(int* __restrict__ p, int n) {
  int i = blockIdx.x * blockDim.x + threadIdx.x;
  if (i < n) p[i] = 0;
}

__global__ void k_count(const int* __restrict__ dst, int* __restrict__ cnt, int E) {
  int e = blockIdx.x * blockDim.x + threadIdx.x;
  if (e < E) atomicAdd(&cnt[dst[e]], 1);
}

__global__ void k_dinv(const int* __restrict__ cnt, float* __restrict__ dinv, int n) {
  int i = blockIdx.x * blockDim.x + threadIdx.x;
  if (i < n) dinv[i] = 1.0f / sqrtf((float)(cnt[i] + 1));  // +1 self loop, deg>0 always
}

// exclusive scan of cnt[0..n) -> row_ptr[0..n], single block of 1024
__global__ __launch_bounds__(1024) void k_scan(const int* __restrict__ cnt,
                                               int* __restrict__ row_ptr, int n) {
  __shared__ int sm[1024];
  __shared__ int carry;
  int tid = threadIdx.x;
  if (tid == 0) carry = 0;
  __syncthreads();
  for (int base = 0; base < n; base += 1024) {
    int i = base + tid;
    int v = (i < n) ? cnt[i] : 0;
    sm[tid] = v;
    __syncthreads();
    for (int off = 1; off < 1024; off <<= 1) {
      int t = (tid >= off) ? sm[tid - off] : 0;
      __syncthreads();
      sm[tid] += t;
      __syncthreads();
    }
    int c = carry;
    if (i < n) row_ptr[i] = c + sm[tid] - v;  // exclusive
    int tot = sm[1023];
    __syncthreads();
    if (tid == 0) carry = c + tot;
    __syncthreads();
  }
  if (threadIdx.x == 0) row_ptr[n] = carry;
}

__global__ void k_copy_int(const int* __restrict__ a, int* __restrict__ b, int n) {
  int i = blockIdx.x * blockDim.x + threadIdx.x;
  if (i < n) b[i] = a[i];
}

__global__ void k_fill(const int* __restrict__ src, const int* __restrict__ dst,
                       int* __restrict__ cursor, int* __restrict__ csr_src, int E) {
  int e = blockIdx.x * blockDim.x + threadIdx.x;
  if (e < E) {
    int pos = atomicAdd(&cursor[dst[e]], 1);
    csr_src[pos] = src[e];
  }
}

// ---------------- fp32 tiled GEMM: C[M,N] = act(A[M,K] @ B[K,N] + bias) ----------------
// 64x64 block tile, BK=16, 256 threads, 4x4 per thread.

template <int RELU, int BIAS>
__global__ __launch_bounds__(256) void k_gemm(const float* __restrict__ A,
                                              const float* __restrict__ B,
                                              const float* __restrict__ bias,
                                              float* __restrict__ C,
                                              int M, int N, int K) {
  __shared__ float As[16][68];  // [k][m], +4 pad keeps float4 alignment
  __shared__ float Bs[16][68];  // [k][n]
  const int bm = blockIdx.y * 64;
  const int bn = blockIdx.x * 64;
  const int tid = threadIdx.x;
  const int tr = (tid >> 4) << 2;   // row offset in tile (0..60)
  const int tc = (tid & 15) << 2;   // col offset in tile (0..60)

  const int lm  = tid >> 2;         // 0..63   (A staging row)
  const int lk  = (tid & 3) << 2;   // 0,4,8,12 (A staging k)
  const int lk2 = tid >> 4;         // 0..15   (B staging k)
  const int ln  = (tid & 15) << 2;  // 0..60   (B staging col)

  const bool arow_ok = (bm + lm) < M;
  const float* Aptr = A + (size_t)(bm + lm) * K + lk;
  const float* Bptr = B + (size_t)lk2 * N + bn + ln;

  float acc[4][4] = {};

  for (int k0 = 0; k0 < K; k0 += 16) {
    float4 a4 = make_float4(0.f, 0.f, 0.f, 0.f);
    if (arow_ok) a4 = *(const float4*)(Aptr + k0);
    float4 b4 = *(const float4*)(Bptr + (size_t)k0 * N);
    As[lk + 0][lm] = a4.x;
    As[lk + 1][lm] = a4.y;
    As[lk + 2][lm] = a4.z;
    As[lk + 3][lm] = a4.w;
    *(float4*)&Bs[lk2][ln] = b4;
    __syncthreads();
#pragma unroll
    for (int k = 0; k < 16; ++k) {
      float4 av = *(const float4*)&As[k][tr];
      float4 bv = *(const float4*)&Bs[k][tc];
      float a[4] = {av.x, av.y, av.z, av.w};
      float b[4] = {bv.x, bv.y, bv.z, bv.w};
#pragma unroll
      for (int i = 0; i < 4; ++i)
#pragma unroll
        for (int j = 0; j < 4; ++j) acc[i][j] += a[i] * b[j];
    }
    __syncthreads();
  }

  float bias_v[4] = {0.f, 0.f, 0.f, 0.f};
  if (BIAS) {
    float4 bb = *(const float4*)(bias + bn + tc);
    bias_v[0] = bb.x; bias_v[1] = bb.y; bias_v[2] = bb.z; bias_v[3] = bb.w;
  }
#pragma unroll
  for (int i = 0; i < 4; ++i) {
    int r = bm + tr + i;
    if (r < M) {
      float4 o;
      o.x = acc[i][0] + bias_v[0];
      o.y = acc[i][1] + bias_v[1];
      o.z = acc[i][2] + bias_v[2];
      o.w = acc[i][3] + bias_v[3];
      if (RELU) {
        o.x = fmaxf(o.x, 0.f); o.y = fmaxf(o.y, 0.f);
        o.z = fmaxf(o.z, 0.f); o.w = fmaxf(o.w, 0.f);
      }
      *(float4*)&C[(size_t)r * N + bn + tc] = o;
    }
  }
}

// ---------------- GCN aggregation (gather form, one wave per node, 256 feats) ----------------
// out[i] = sum_{e: dst==i} t[src]*dinv[src]*dinv[i] + t[i]*dinv[i]^2 + bias

__global__ __launch_bounds__(256) void k_agg(const float* __restrict__ t,
                                             const int* __restrict__ row_ptr,
                                             const int* __restrict__ csr_src,
                                             const float* __restrict__ dinv,
                                             const float* __restrict__ bias,
                                             float* __restrict__ out, int n_nodes) {
  int w = (int)((blockIdx.x * 256 + threadIdx.x) >> 6);
  int lane = threadIdx.x & 63;
  if (w >= n_nodes) return;
  float di = dinv[w];
  const float4* trow = (const float4*)(t + (size_t)w * 256);
  float4 v = trow[lane];
  float sw = di * di;
  float ax = v.x * sw, ay = v.y * sw, az = v.z * sw, aw = v.w * sw;
  int e0 = row_ptr[w], e1 = row_ptr[w + 1];
  for (int e = e0; e < e1; ++e) {
    int s = csr_src[e];
    float wgt = dinv[s] * di;
    const float4* srow = (const float4*)(t + (size_t)s * 256);
    float4 u = srow[lane];
    ax += u.x * wgt; ay += u.y * wgt; az += u.z * wgt; aw += u.w * wgt;
  }
  const float4 b = ((const float4*)bias)[lane];
  float4 o;
  o.x = ax + b.x; o.y = ay + b.y; o.z = az + b.z; o.w = aw + b.w;
  ((float4*)(out + (size_t)w * 256))[lane] = o;
}

// ---------------- classifier: out[M,2] = h[M,K] @ Wc[K,2] + bc ----------------

__global__ __launch_bounds__(256) void k_cls(const float* __restrict__ h,
                                             const float* __restrict__ Wc,
                                             const float* __restrict__ bc,
                                             float* __restrict__ out, int M, int K) {
  __shared__ float w[512];
  for (int i = threadIdx.x; i < 2 * K; i += 256) w[i] = Wc[i];
  __syncthreads();
  int i = blockIdx.x * 256 + threadIdx.x;
  if (i >= M) return;
  float a0 = bc[0], a1 = bc[1];
  const float* hr = h + (size_t)i * K;
  for (int k = 0; k < K; ++k) {
    float a = hr[k];
    a0 += a * w[2 * k];
    a1 += a * w[2 * k + 1];
  }
  out[2 * i] = a0;
  out[2 * i + 1] = a1;
}

// ---------------- launch ----------------

extern "C" void kernel_launch(void* const* d_in, const int* in_sizes, int n_in,
                              void* d_out, int out_size, void* d_ws, size_t ws_size,
                              hipStream_t stream) {
  const float* x   = (const float*)d_in[0];
  const int*   ei  = (const int*)d_in[1];
  const float* W1  = (const float*)d_in[2];
  const float* b1  = (const float*)d_in[3];
  const float* Wg1 = (const float*)d_in[4];
  const float* bg1 = (const float*)d_in[5];
  const float* Wg2 = (const float*)d_in[6];
  const float* bg2 = (const float*)d_in[7];
  const float* W2  = (const float*)d_in[8];
  const float* b2  = (const float*)d_in[9];
  const float* Wc  = (const float*)d_in[10];
  const float* bc  = (const float*)d_in[11];
  float* out = (float*)d_out;

  const int hid     = in_sizes[3];            // 256
  const int in_dim  = in_sizes[2] / hid;      // 768
  const int out_dim = in_sizes[9];            // 128
  const int N       = in_sizes[0] / in_dim;   // 50000
  const int E       = in_sizes[1] / 2;        // 800000
  const int Batch   = out_size / 2;           // 1024

  const int* srcI = ei;
  const int* dstI = ei + E;

  char* ws = (char*)d_ws;
  size_t off = 0;
  auto alloc = [&](size_t bytes) -> void* {
    void* p = ws + off;
    off = (off + bytes + 255) & ~(size_t)255;
    return p;
  };
  float* bufA   = (float*)alloc((size_t)N * hid * 4);       // h0, then h1
  float* bufB   = (float*)alloc((size_t)N * hid * 4);       // t1, then t2
  float* agg2   = (float*)alloc((size_t)Batch * hid * 4);
  float* h3     = (float*)alloc((size_t)Batch * out_dim * 4);
  float* dinv   = (float*)alloc((size_t)N * 4);
  int*   cnt    = (int*)alloc((size_t)N * 4);
  int*   rowp   = (int*)alloc((size_t)(N + 1) * 4);
  int*   cursor = (int*)alloc((size_t)N * 4);
  int*   csrs   = (int*)alloc((size_t)E * 4);
  (void)ws_size; (void)n_in;

  dim3 blk(256);

  // CSR + norm build (recomputed every call; ws is re-poisoned)
  k_zero_int<<<(N + 255) / 256, blk, 0, stream>>>(cnt, N);
  k_count<<<(E + 255) / 256, blk, 0, stream>>>(dstI, cnt, E);
  k_dinv<<<(N + 255) / 256, blk, 0, stream>>>(cnt, dinv, N);
  k_scan<<<1, 1024, 0, stream>>>(cnt, rowp, N);
  k_copy_int<<<(N + 255) / 256, blk, 0, stream>>>(rowp, cursor, N);
  k_fill<<<(E + 255) / 256, blk, 0, stream>>>(srcI, dstI, cursor, csrs, E);

  // h0 = relu(x @ W1 + b1)
  k_gemm<1, 1><<<dim3(hid / 64, (N + 63) / 64), blk, 0, stream>>>(x, W1, b1, bufA, N, hid, in_dim);
  // t1 = h0 @ Wg1
  k_gemm<0, 0><<<dim3(hid / 64, (N + 63) / 64), blk, 0, stream>>>(bufA, Wg1, nullptr, bufB, N, hid, hid);
  // h1 = aggregate(t1) + bg1
  k_agg<<<(N + 3) / 4, blk, 0, stream>>>(bufB, rowp, csrs, dinv, bg1, bufA, N);
  // t2 = h1 @ Wg2
  k_gemm<0, 0><<<dim3(hid / 64, (N + 63) / 64), blk, 0, stream>>>(bufA, Wg2, nullptr, bufB, N, hid, hid);
  // conv2 aggregation only for rows [0, Batch)
  k_agg<<<(Batch + 3) / 4, blk, 0, stream>>>(bufB, rowp, csrs, dinv, bg2, agg2, Batch);
  // h3 = relu(agg2 @ W2 + b2)
  k_gemm<1, 1><<<dim3(out_dim / 64, (Batch + 63) / 64), blk, 0, stream>>>(agg2, W2, b2, h3, Batch, out_dim, hid);
  // logits = h3 @ Wc + bc
  k_cls<<<(Batch + 255) / 256, blk, 0, stream>>>(h3, Wc, bc, out, Batch, out_dim);
}

// Round 2
// 612.509 us; speedup vs baseline: 1.5905x; 1.5905x over previous
//
#include <hip/hip_runtime.h>
#include <hip/hip_bf16.h>
#include <cstdint>
#include <cstddef>
#include <type_traits>

typedef _Float16 half8 __attribute__((ext_vector_type(8)));
typedef _Float16 half4v __attribute__((ext_vector_type(4)));
typedef float float4v __attribute__((ext_vector_type(4)));

// ---------------- CSR build ----------------

__global__ void k_zero_int(int* __restrict__ p, int n) {
  int i = blockIdx.x * blockDim.x + threadIdx.x;
  if (i < n) p[i] = 0;
}

__global__ void k_count(const int* __restrict__ dst, int* __restrict__ cnt, int E) {
  int e = blockIdx.x * blockDim.x + threadIdx.x;
  if (e < E) atomicAdd(&cnt[dst[e]], 1);
}

__global__ void k_dinv(const int* __restrict__ cnt, float* __restrict__ dinv, int n) {
  int i = blockIdx.x * blockDim.x + threadIdx.x;
  if (i < n) dinv[i] = 1.0f / sqrtf((float)(cnt[i] + 1));  // +1 self loop
}

// hierarchical exclusive scan: local (per-1024 block) -> sums -> fixup
__global__ __launch_bounds__(1024) void k_scan_local(const int* __restrict__ cnt,
                                                     int* __restrict__ rowp,
                                                     int* __restrict__ bsum, int n) {
  __shared__ int sm[1024];
  int tid = threadIdx.x;
  int i = blockIdx.x * 1024 + tid;
  int v = (i < n) ? cnt[i] : 0;
  sm[tid] = v;
  __syncthreads();
  for (int off = 1; off < 1024; off <<= 1) {
    int t = (tid >= off) ? sm[tid - off] : 0;
    __syncthreads();
    sm[tid] += t;
    __syncthreads();
  }
  if (i < n) rowp[i] = sm[tid] - v;  // exclusive (pre-fixup)
  if (tid == 1023) bsum[blockIdx.x] = sm[1023];
}

__global__ __launch_bounds__(1024) void k_scan_sums(int* __restrict__ bsum, int nb) {
  __shared__ int sm[1024];
  int tid = threadIdx.x;
  int v = (tid < nb) ? bsum[tid] : 0;
  sm[tid] = v;
  __syncthreads();
  for (int off = 1; off < 1024; off <<= 1) {
    int t = (tid >= off) ? sm[tid - off] : 0;
    __syncthreads();
    sm[tid] += t;
    __syncthreads();
  }
  if (tid < nb) bsum[tid] = sm[tid] - v;  // exclusive
}

__global__ void k_scan_fixup(int* __restrict__ rowp, const int* __restrict__ bsum,
                             int n, int E) {
  int i = blockIdx.x * blockDim.x + threadIdx.x;
  if (i < n) rowp[i] += bsum[i >> 10];
  if (i == 0) rowp[n] = E;  // total edge count known analytically
}

__global__ void k_copy_int(const int* __restrict__ a, int* __restrict__ b, int n) {
  int i = blockIdx.x * blockDim.x + threadIdx.x;
  if (i < n) b[i] = a[i];
}

__global__ void k_fill(const int* __restrict__ src, const int* __restrict__ dst,
                       int* __restrict__ cursor, int* __restrict__ csr_src, int E) {
  int e = blockIdx.x * blockDim.x + threadIdx.x;
  if (e < E) {
    int pos = atomicAdd(&cursor[dst[e]], 1);
    csr_src[pos] = src[e];
  }
}

// ---------------- weight convert: Bt[n*K+k] = (f16) W[k*N+n] ----------------

__global__ void k_w_to_f16_t(const float* __restrict__ W, _Float16* __restrict__ Bt,
                             int K, int N) {
  int idx = blockIdx.x * blockDim.x + threadIdx.x;
  if (idx < K * N) {
    int n = idx / K, k = idx - n * K;
    Bt[idx] = (_Float16)W[(size_t)k * N + n];
  }
}

// ---------------- fp16 MFMA GEMM: out[M,N] = act(A[M,K] @ Bt^T + bias) ----------------
// A: fp32 or fp16 row-major [M,K]; Bt: fp16 [N,K] (pre-transposed weights).
// 128x128 block tile, BK=32, 256 threads = 4 waves in 2x2, 16 MFMA/k-step/wave.

#define LDSS 40  // LDS row stride in halves (32 + 8 pad, keeps 16B align, 2-way banks)

template <typename AT, int RELU, int BIAS>
__global__ __launch_bounds__(256) void k_gemm_mfma(const AT* __restrict__ A,
                                                   const _Float16* __restrict__ Bt,
                                                   const float* __restrict__ bias,
                                                   _Float16* __restrict__ out,
                                                   int M, int N, int K) {
  __shared__ _Float16 Asm[128 * LDSS];
  __shared__ _Float16 Bsm[128 * LDSS];
  const int tid = threadIdx.x;
  const int bm = blockIdx.y * 128;
  const int bn = blockIdx.x * 128;
  const int wave = tid >> 6;
  const int wm = (wave >> 1) * 64;
  const int wn = (wave & 1) * 64;
  const int quad = (tid & 63) >> 4;
  const int l15 = tid & 15;

  float4v acc[4][4];
#pragma unroll
  for (int i = 0; i < 4; ++i)
#pragma unroll
    for (int j = 0; j < 4; ++j) acc[i][j] = (float4v){0.f, 0.f, 0.f, 0.f};

  for (int k0 = 0; k0 < K; k0 += 32) {
#pragma unroll
    for (int p = 0; p < 2; ++p) {
      int chunk = tid + p * 256;  // 0..511
      int r = chunk >> 2;         // 0..127
      int c = chunk & 3;          // 0..3 (8-half chunks)
      // A tile
      int gr = bm + r;
      half8 av = {};
      if (gr < M) {
        if constexpr (std::is_same_v<AT, float>) {
          const float* s = A + (size_t)gr * K + k0 + c * 8;
          float4 f0 = *(const float4*)s;
          float4 f1 = *(const float4*)(s + 4);
          av[0] = (_Float16)f0.x; av[1] = (_Float16)f0.y;
          av[2] = (_Float16)f0.z; av[3] = (_Float16)f0.w;
          av[4] = (_Float16)f1.x; av[5] = (_Float16)f1.y;
          av[6] = (_Float16)f1.z; av[7] = (_Float16)f1.w;
        } else {
          av = *(const half8*)(A + (size_t)gr * K + k0 + c * 8);
        }
      }
      *(half8*)(Asm + r * LDSS + c * 8) = av;
      // B tile (N is a multiple of 128 -> no guard)
      half8 bv = *(const half8*)(Bt + (size_t)(bn + r) * K + k0 + c * 8);
      *(half8*)(Bsm + r * LDSS + c * 8) = bv;
    }
    __syncthreads();
    half8 af[4], bf[4];
#pragma unroll
    for (int i = 0; i < 4; ++i)
      af[i] = *(const half8*)(Asm + (wm + i * 16 + l15) * LDSS + quad * 8);
#pragma unroll
    for (int j = 0; j < 4; ++j)
      bf[j] = *(const half8*)(Bsm + (wn + j * 16 + l15) * LDSS + quad * 8);
#pragma unroll
    for (int i = 0; i < 4; ++i)
#pragma unroll
      for (int j = 0; j < 4; ++j)
        acc[i][j] = __builtin_amdgcn_mfma_f32_16x16x32_f16(af[i], bf[j], acc[i][j], 0, 0, 0);
    __syncthreads();
  }

  // epilogue: C/D layout col=lane&15, row=quad*4+reg
#pragma unroll
  for (int j = 0; j < 4; ++j) {
    int c = bn + wn + j * 16 + l15;
    float bv = BIAS ? bias[c] : 0.f;
#pragma unroll
    for (int i = 0; i < 4; ++i) {
      int rbase = bm + wm + i * 16 + quad * 4;
      float4v a = acc[i][j];
#pragma unroll
      for (int reg = 0; reg < 4; ++reg) {
        int r = rbase + reg;
        if (r < M) {
          float v = a[reg] + bv;
          if (RELU) v = fmaxf(v, 0.f);
          out[(size_t)r * N + c] = (_Float16)v;
        }
      }
    }
  }
}

// ---------------- fp32 tiled GEMM (tail): C = act(A @ B + bias) ----------------

template <int RELU, int BIAS>
__global__ __launch_bounds__(256) void k_gemm(const float* __restrict__ A,
                                              const float* __restrict__ B,
                                              const float* __restrict__ bias,
                                              float* __restrict__ C,
                                              int M, int N, int K) {
  __shared__ float As[16][68];
  __shared__ float Bs[16][68];
  const int bm = blockIdx.y * 64;
  const int bn = blockIdx.x * 64;
  const int tid = threadIdx.x;
  const int tr = (tid >> 4) << 2;
  const int tc = (tid & 15) << 2;
  const int lm  = tid >> 2;
  const int lk  = (tid & 3) << 2;
  const int lk2 = tid >> 4;
  const int ln  = (tid & 15) << 2;
  const bool arow_ok = (bm + lm) < M;
  const float* Aptr = A + (size_t)(bm + lm) * K + lk;
  const float* Bptr = B + (size_t)lk2 * N + bn + ln;
  float acc[4][4] = {};
  for (int k0 = 0; k0 < K; k0 += 16) {
    float4 a4 = make_float4(0.f, 0.f, 0.f, 0.f);
    if (arow_ok) a4 = *(const float4*)(Aptr + k0);
    float4 b4 = *(const float4*)(Bptr + (size_t)k0 * N);
    As[lk + 0][lm] = a4.x;
    As[lk + 1][lm] = a4.y;
    As[lk + 2][lm] = a4.z;
    As[lk + 3][lm] = a4.w;
    *(float4*)&Bs[lk2][ln] = b4;
    __syncthreads();
#pragma unroll
    for (int k = 0; k < 16; ++k) {
      float4 av = *(const float4*)&As[k][tr];
      float4 bv = *(const float4*)&Bs[k][tc];
      float a[4] = {av.x, av.y, av.z, av.w};
      float b[4] = {bv.x, bv.y, bv.z, bv.w};
#pragma unroll
      for (int i = 0; i < 4; ++i)
#pragma unroll
        for (int j = 0; j < 4; ++j) acc[i][j] += a[i] * b[j];
    }
    __syncthreads();
  }
  float bias_v[4] = {0.f, 0.f, 0.f, 0.f};
  if (BIAS) {
    float4 bb = *(const float4*)(bias + bn + tc);
    bias_v[0] = bb.x; bias_v[1] = bb.y; bias_v[2] = bb.z; bias_v[3] = bb.w;
  }
#pragma unroll
  for (int i = 0; i < 4; ++i) {
    int r = bm + tr + i;
    if (r < M) {
      float4 o;
      o.x = acc[i][0] + bias_v[0];
      o.y = acc[i][1] + bias_v[1];
      o.z = acc[i][2] + bias_v[2];
      o.w = acc[i][3] + bias_v[3];
      if (RELU) {
        o.x = fmaxf(o.x, 0.f); o.y = fmaxf(o.y, 0.f);
        o.z = fmaxf(o.z, 0.f); o.w = fmaxf(o.w, 0.f);
      }
      *(float4*)&C[(size_t)r * N + bn + tc] = o;
    }
  }
}

// ---------------- GCN aggregation (gather, one wave/node, 256 feats, fp16 t) --------

template <typename OT>
__global__ __launch_bounds__(256) void k_agg(const _Float16* __restrict__ t,
                                             const int* __restrict__ row_ptr,
                                             const int* __restrict__ csr_src,
                                             const float* __restrict__ dinv,
                                             const float* __restrict__ bias,
                                             OT* __restrict__ out, int n_nodes) {
  int w = (int)((blockIdx.x * 256 + threadIdx.x) >> 6);
  int lane = threadIdx.x & 63;
  if (w >= n_nodes) return;
  float di = dinv[w];
  half4v v = *(const half4v*)(t + (size_t)w * 256 + lane * 4);
  float sw = di * di;
  float ax = (float)v[0] * sw, ay = (float)v[1] * sw, az = (float)v[2] * sw, aw = (float)v[3] * sw;
  int e0 = row_ptr[w], e1 = row_ptr[w + 1];
  for (int e = e0; e < e1; ++e) {
    int s = csr_src[e];
    float wgt = dinv[s] * di;
    half4v u = *(const half4v*)(t + (size_t)s * 256 + lane * 4);
    ax += (float)u[0] * wgt; ay += (float)u[1] * wgt;
    az += (float)u[2] * wgt; aw += (float)u[3] * wgt;
  }
  const float4 b = ((const float4*)bias)[lane];
  if constexpr (std::is_same_v<OT, float>) {
    float4 o;
    o.x = ax + b.x; o.y = ay + b.y; o.z = az + b.z; o.w = aw + b.w;
    ((float4*)(out + (size_t)w * 256))[lane] = o;
  } else {
    half4v o;
    o[0] = (_Float16)(ax + b.x); o[1] = (_Float16)(ay + b.y);
    o[2] = (_Float16)(az + b.z); o[3] = (_Float16)(aw + b.w);
    *(half4v*)(out + (size_t)w * 256 + lane * 4) = o;
  }
}

// ---------------- classifier: out[M,2] = h[M,K] @ Wc[K,2] + bc ----------------

__global__ __launch_bounds__(256) void k_cls(const float* __restrict__ h,
                                             const float* __restrict__ Wc,
                                             const float* __restrict__ bc,
                                             float* __restrict__ out, int M, int K) {
  __shared__ float w[512];
  for (int i = threadIdx.x; i < 2 * K; i += 256) w[i] = Wc[i];
  __syncthreads();
  int i = blockIdx.x * 256 + threadIdx.x;
  if (i >= M) return;
  float a0 = bc[0], a1 = bc[1];
  const float* hr = h + (size_t)i * K;
  for (int k = 0; k < K; ++k) {
    float a = hr[k];
    a0 += a * w[2 * k];
    a1 += a * w[2 * k + 1];
  }
  out[2 * i] = a0;
  out[2 * i + 1] = a1;
}

// ---------------- launch ----------------

extern "C" void kernel_launch(void* const* d_in, const int* in_sizes, int n_in,
                              void* d_out, int out_size, void* d_ws, size_t ws_size,
                              hipStream_t stream) {
  const float* x   = (const float*)d_in[0];
  const int*   ei  = (const int*)d_in[1];
  const float* W1  = (const float*)d_in[2];
  const float* b1  = (const float*)d_in[3];
  const float* Wg1 = (const float*)d_in[4];
  const float* bg1 = (const float*)d_in[5];
  const float* Wg2 = (const float*)d_in[6];
  const float* bg2 = (const float*)d_in[7];
  const float* W2  = (const float*)d_in[8];
  const float* b2  = (const float*)d_in[9];
  const float* Wc  = (const float*)d_in[10];
  const float* bc  = (const float*)d_in[11];
  float* out = (float*)d_out;

  const int hid     = in_sizes[3];            // 256
  const int in_dim  = in_sizes[2] / hid;      // 768
  const int out_dim = in_sizes[9];            // 128
  const int N       = in_sizes[0] / in_dim;   // 50000
  const int E       = in_sizes[1] / 2;        // 800000
  const int Batch   = out_size / 2;           // 1024

  const int* srcI = ei;
  const int* dstI = ei + E;

  char* ws = (char*)d_ws;
  size_t off = 0;
  auto alloc = [&](size_t bytes) -> void* {
    void* p = ws + off;
    off = (off + bytes + 255) & ~(size_t)255;
    return p;
  };
  _Float16* h0h  = (_Float16*)alloc((size_t)N * hid * 2);
  _Float16* t1h  = (_Float16*)alloc((size_t)N * hid * 2);
  _Float16* h1h  = (_Float16*)alloc((size_t)N * hid * 2);
  _Float16* t2h  = (_Float16*)alloc((size_t)N * hid * 2);
  _Float16* W1t  = (_Float16*)alloc((size_t)in_dim * hid * 2);
  _Float16* Wg1t = (_Float16*)alloc((size_t)hid * hid * 2);
  _Float16* Wg2t = (_Float16*)alloc((size_t)hid * hid * 2);
  float* agg2    = (float*)alloc((size_t)Batch * hid * 4);
  float* h3      = (float*)alloc((size_t)Batch * out_dim * 4);
  float* dinv    = (float*)alloc((size_t)N * 4);
  int*   cnt     = (int*)alloc((size_t)N * 4);
  int*   rowp    = (int*)alloc((size_t)(N + 1) * 4);
  int*   bsum    = (int*)alloc((size_t)1024 * 4);
  int*   cursor  = (int*)alloc((size_t)N * 4);
  int*   csrs    = (int*)alloc((size_t)E * 4);
  (void)ws_size; (void)n_in;

  dim3 blk(256);
  const int nb = (N + 1023) / 1024;

  // CSR + norm build
  k_zero_int<<<(N + 255) / 256, blk, 0, stream>>>(cnt, N);
  k_count<<<(E + 255) / 256, blk, 0, stream>>>(dstI, cnt, E);
  k_dinv<<<(N + 255) / 256, blk, 0, stream>>>(cnt, dinv, N);
  k_scan_local<<<nb, 1024, 0, stream>>>(cnt, rowp, bsum, N);
  k_scan_sums<<<1, 1024, 0, stream>>>(bsum, nb);
  k_scan_fixup<<<(N + 255) / 256, blk, 0, stream>>>(rowp, bsum, N, E);
  k_copy_int<<<(N + 255) / 256, blk, 0, stream>>>(rowp, cursor, N);
  k_fill<<<(E + 255) / 256, blk, 0, stream>>>(srcI, dstI, cursor, csrs, E);

  // weight convert + transpose (fp16)
  k_w_to_f16_t<<<(in_dim * hid + 255) / 256, blk, 0, stream>>>(W1, W1t, in_dim, hid);
  k_w_to_f16_t<<<(hid * hid + 255) / 256, blk, 0, stream>>>(Wg1, Wg1t, hid, hid);
  k_w_to_f16_t<<<(hid * hid + 255) / 256, blk, 0, stream>>>(Wg2, Wg2t, hid, hid);

  dim3 gemm_grid(hid / 128, (N + 127) / 128);
  // h0 = relu(x @ W1 + b1)   (A fp32 -> converted in staging)
  k_gemm_mfma<float, 1, 1><<<gemm_grid, blk, 0, stream>>>(x, W1t, b1, h0h, N, hid, in_dim);
  // t1 = h0 @ Wg1
  k_gemm_mfma<_Float16, 0, 0><<<gemm_grid, blk, 0, stream>>>(h0h, Wg1t, nullptr, t1h, N, hid, hid);
  // h1 = aggregate(t1) + bg1  (fp16 out)
  k_agg<_Float16><<<(N + 3) / 4, blk, 0, stream>>>(t1h, rowp, csrs, dinv, bg1, h1h, N);
  // t2 = h1 @ Wg2
  k_gemm_mfma<_Float16, 0, 0><<<gemm_grid, blk, 0, stream>>>(h1h, Wg2t, nullptr, t2h, N, hid, hid);
  // conv2 aggregation only for rows [0, Batch)  (fp32 out)
  k_agg<float><<<(Batch + 3) / 4, blk, 0, stream>>>(t2h, rowp, csrs, dinv, bg2, agg2, Batch);
  // h3 = relu(agg2 @ W2 + b2)
  k_gemm<1, 1><<<dim3(out_dim / 64, (Batch + 63) / 64), blk, 0, stream>>>(agg2, W2, b2, h3, Batch, out_dim, hid);
  // logits = h3 @ Wc + bc
  k_cls<<<(Batch + 255) / 256, blk, 0, stream>>>(h3, Wc, bc, out, Batch, out_dim);
}

// Round 4
// 551.126 us; speedup vs baseline: 1.7676x; 1.1114x over previous
//
#include <hip/hip_runtime.h>
#include <hip/hip_bf16.h>
#include <cstdint>
#include <cstddef>
#include <type_traits>

typedef _Float16 half8 __attribute__((ext_vector_type(8)));
typedef _Float16 half4v __attribute__((ext_vector_type(4)));
typedef float float4v __attribute__((ext_vector_type(4)));

// ---------------- CSR build ----------------

__global__ void k_zero_int(int* __restrict__ p, int n) {
  int i = blockIdx.x * blockDim.x + threadIdx.x;
  if (i < n) p[i] = 0;
}

__global__ void k_count(const int* __restrict__ dst, int* __restrict__ cnt, int E) {
  int e = blockIdx.x * blockDim.x + threadIdx.x;
  if (e < E) atomicAdd(&cnt[dst[e]], 1);
}

// hierarchical exclusive scan: local (per-1024 block) -> sums -> fixup
__global__ __launch_bounds__(1024) void k_scan_local(const int* __restrict__ cnt,
                                                     int* __restrict__ rowp,
                                                     int* __restrict__ bsum, int n) {
  __shared__ int sm[1024];
  int tid = threadIdx.x;
  int i = blockIdx.x * 1024 + tid;
  int v = (i < n) ? cnt[i] : 0;
  sm[tid] = v;
  __syncthreads();
  for (int off = 1; off < 1024; off <<= 1) {
    int t = (tid >= off) ? sm[tid - off] : 0;
    __syncthreads();
    sm[tid] += t;
    __syncthreads();
  }
  if (i < n) rowp[i] = sm[tid] - v;  // exclusive (pre-fixup)
  if (tid == 1023) bsum[blockIdx.x] = sm[1023];
}

__global__ __launch_bounds__(1024) void k_scan_sums(int* __restrict__ bsum, int nb) {
  __shared__ int sm[1024];
  int tid = threadIdx.x;
  int v = (tid < nb) ? bsum[tid] : 0;
  sm[tid] = v;
  __syncthreads();
  for (int off = 1; off < 1024; off <<= 1) {
    int t = (tid >= off) ? sm[tid - off] : 0;
    __syncthreads();
    sm[tid] += t;
    __syncthreads();
  }
  if (tid < nb) bsum[tid] = sm[tid] - v;  // exclusive
}

// fixup + cursor copy + dinv, fused
__global__ void k_finalize(int* __restrict__ rowp, const int* __restrict__ bsum,
                           const int* __restrict__ cnt, int* __restrict__ cursor,
                           float* __restrict__ dinv, int n, int E) {
  int i = blockIdx.x * blockDim.x + threadIdx.x;
  if (i < n) {
    int v = rowp[i] + bsum[i >> 10];
    rowp[i] = v;
    cursor[i] = v;
    dinv[i] = rsqrtf((float)(cnt[i] + 1));  // +1 self loop
  }
  if (i == 0) rowp[n] = E;
}

__global__ void k_fill(const int* __restrict__ src, const int* __restrict__ dst,
                       int* __restrict__ cursor, int* __restrict__ csr_src, int E) {
  int e = blockIdx.x * blockDim.x + threadIdx.x;
  if (e < E) {
    int pos = atomicAdd(&cursor[dst[e]], 1);
    csr_src[pos] = src[e];
  }
}

// ---------------- fused weight convert+transpose (3 matrices in one launch) --------

__global__ void k_w_convert_all(const float* __restrict__ W1, const float* __restrict__ Wg1,
                                const float* __restrict__ Wg2, _Float16* __restrict__ W1t,
                                _Float16* __restrict__ Wg1t, _Float16* __restrict__ Wg2t,
                                int in_dim, int hid) {
  int idx = blockIdx.x * blockDim.x + threadIdx.x;
  int n1 = in_dim * hid;
  int n2 = hid * hid;
  if (idx < n1) {
    int n = idx / in_dim, k = idx - n * in_dim;
    W1t[idx] = (_Float16)W1[(size_t)k * hid + n];
  } else if (idx < n1 + n2) {
    int i2 = idx - n1;
    int n = i2 / hid, k = i2 - n * hid;
    Wg1t[i2] = (_Float16)Wg1[(size_t)k * hid + n];
  } else if (idx < n1 + 2 * n2) {
    int i2 = idx - n1 - n2;
    int n = i2 / hid, k = i2 - n * hid;
    Wg2t[i2] = (_Float16)Wg2[(size_t)k * hid + n];
  }
}

// ---------------- fp16 MFMA GEMM, double-buffered + register prefetch ----------------
// out[M,N] = act(A[M,K] @ Bt^T + bias); A fp32 or fp16 row-major; Bt fp16 [N,K].
// 128x128 tile, BK=32, 256 threads = 4 waves (2x2), one barrier per k-step.
// NOTE: no device lambdas here — capturing lambdas with ext_vector arrays
// crashed the clang-22 frontend in the previous round.

#define LDSS 40  // LDS row stride in halves (32 + 8 pad -> conflict-free b128 reads)

template <typename AT>
__device__ __forceinline__ half8 load_row_h8(const AT* __restrict__ p, bool ok) {
  half8 v = {};
  if (ok) {
    if constexpr (std::is_same_v<AT, float>) {
      float4 f0 = *(const float4*)p;
      float4 f1 = *(const float4*)(p + 4);
      v[0] = (_Float16)f0.x; v[1] = (_Float16)f0.y;
      v[2] = (_Float16)f0.z; v[3] = (_Float16)f0.w;
      v[4] = (_Float16)f1.x; v[5] = (_Float16)f1.y;
      v[6] = (_Float16)f1.z; v[7] = (_Float16)f1.w;
    } else {
      v = *(const half8*)p;
    }
  }
  return v;
}

template <typename AT, int RELU, int BIAS>
__global__ __launch_bounds__(256, 3) void k_gemm_mfma(const AT* __restrict__ A,
                                                      const _Float16* __restrict__ Bt,
                                                      const float* __restrict__ bias,
                                                      _Float16* __restrict__ out,
                                                      int M, int N, int K) {
  __shared__ _Float16 Asm[2][128 * LDSS];
  __shared__ _Float16 Bsm[2][128 * LDSS];
  const int tid = threadIdx.x;
  const int bm = blockIdx.y * 128;
  const int bn = blockIdx.x * 128;
  const int wave = tid >> 6;
  const int wm = (wave >> 1) * 64;
  const int wn = (wave & 1) * 64;
  const int quad = (tid & 63) >> 4;
  const int l15 = tid & 15;
  const int r0 = tid >> 2;        // 0..63 (this thread stages rows r0 and r0+64)
  const int c0 = (tid & 3) * 8;   // half-offset within the 32-wide k-slab

  const int gr0 = bm + r0, gr1 = bm + r0 + 64;
  const bool ok0 = gr0 < M, ok1 = gr1 < M;
  const AT* Ap0 = A + (size_t)gr0 * K + c0;
  const AT* Ap1 = A + (size_t)gr1 * K + c0;
  const _Float16* Bp0 = Bt + (size_t)(bn + r0) * K + c0;
  const _Float16* Bp1 = Bt + (size_t)(bn + r0 + 64) * K + c0;

  _Float16* As0 = &Asm[0][0] + r0 * LDSS + c0;
  _Float16* As1 = &Asm[0][0] + (r0 + 64) * LDSS + c0;
  _Float16* Bs0 = &Bsm[0][0] + r0 * LDSS + c0;
  _Float16* Bs1 = &Bsm[0][0] + (r0 + 64) * LDSS + c0;
  const int bufstep = 128 * LDSS;

  float4v acc[4][4];
#pragma unroll
  for (int i = 0; i < 4; ++i)
#pragma unroll
    for (int j = 0; j < 4; ++j) acc[i][j] = (float4v){0.f, 0.f, 0.f, 0.f};

  // prologue: load tile 0 and stage into buffer 0
  half8 pa0 = load_row_h8<AT>(Ap0, ok0);
  half8 pa1 = load_row_h8<AT>(Ap1, ok1);
  half8 pb0 = *(const half8*)Bp0;
  half8 pb1 = *(const half8*)Bp1;
  *(half8*)As0 = pa0;
  *(half8*)As1 = pa1;
  *(half8*)Bs0 = pb0;
  *(half8*)Bs1 = pb1;

  const int nk = K >> 5;
  int buf = 0;
  for (int kt = 0; kt < nk; ++kt) {
    __syncthreads();  // lds[buf] visible; everyone done reading lds[buf^1]
    if (kt + 1 < nk) {
      int k0 = (kt + 1) << 5;
      pa0 = load_row_h8<AT>(Ap0 + k0, ok0);
      pa1 = load_row_h8<AT>(Ap1 + k0, ok1);
      pb0 = *(const half8*)(Bp0 + k0);
      pb1 = *(const half8*)(Bp1 + k0);
    }
    const _Float16* Ab = &Asm[0][0] + buf * bufstep;
    const _Float16* Bb = &Bsm[0][0] + buf * bufstep;
    half8 af[4], bf[4];
#pragma unroll
    for (int i = 0; i < 4; ++i)
      af[i] = *(const half8*)(Ab + (wm + i * 16 + l15) * LDSS + quad * 8);
#pragma unroll
    for (int j = 0; j < 4; ++j)
      bf[j] = *(const half8*)(Bb + (wn + j * 16 + l15) * LDSS + quad * 8);
#pragma unroll
    for (int i = 0; i < 4; ++i)
#pragma unroll
      for (int j = 0; j < 4; ++j)
        acc[i][j] = __builtin_amdgcn_mfma_f32_16x16x32_f16(af[i], bf[j], acc[i][j], 0, 0, 0);
    if (kt + 1 < nk) {
      int nbuf = buf ^ 1;
      *(half8*)(As0 + nbuf * bufstep) = pa0;
      *(half8*)(As1 + nbuf * bufstep) = pa1;
      *(half8*)(Bs0 + nbuf * bufstep) = pb0;
      *(half8*)(Bs1 + nbuf * bufstep) = pb1;
    }
    buf ^= 1;
  }

  // epilogue: C/D layout col=lane&15, row=quad*4+reg
#pragma unroll
  for (int j = 0; j < 4; ++j) {
    int c = bn + wn + j * 16 + l15;
    float bv = BIAS ? bias[c] : 0.f;
#pragma unroll
    for (int i = 0; i < 4; ++i) {
      int rbase = bm + wm + i * 16 + quad * 4;
      float4v a = acc[i][j];
#pragma unroll
      for (int reg = 0; reg < 4; ++reg) {
        int r = rbase + reg;
        if (r < M) {
          float v = a[reg] + bv;
          if (RELU) v = fmaxf(v, 0.f);
          out[(size_t)r * N + c] = (_Float16)v;
        }
      }
    }
  }
}

// ---------------- fp32 tiled GEMM (tail): C = act(A @ B + bias) ----------------

template <int RELU, int BIAS>
__global__ __launch_bounds__(256) void k_gemm(const float* __restrict__ A,
                                              const float* __restrict__ B,
                                              const float* __restrict__ bias,
                                              float* __restrict__ C,
                                              int M, int N, int K) {
  __shared__ float As[16][68];
  __shared__ float Bs[16][68];
  const int bm = blockIdx.y * 64;
  const int bn = blockIdx.x * 64;
  const int tid = threadIdx.x;
  const int tr = (tid >> 4) << 2;
  const int tc = (tid & 15) << 2;
  const int lm  = tid >> 2;
  const int lk  = (tid & 3) << 2;
  const int lk2 = tid >> 4;
  const int ln  = (tid & 15) << 2;
  const bool arow_ok = (bm + lm) < M;
  const float* Aptr = A + (size_t)(bm + lm) * K + lk;
  const float* Bptr = B + (size_t)lk2 * N + bn + ln;
  float acc[4][4] = {};
  for (int k0 = 0; k0 < K; k0 += 16) {
    float4 a4 = make_float4(0.f, 0.f, 0.f, 0.f);
    if (arow_ok) a4 = *(const float4*)(Aptr + k0);
    float4 b4 = *(const float4*)(Bptr + (size_t)k0 * N);
    As[lk + 0][lm] = a4.x;
    As[lk + 1][lm] = a4.y;
    As[lk + 2][lm] = a4.z;
    As[lk + 3][lm] = a4.w;
    *(float4*)&Bs[lk2][ln] = b4;
    __syncthreads();
#pragma unroll
    for (int k = 0; k < 16; ++k) {
      float4 av = *(const float4*)&As[k][tr];
      float4 bv = *(const float4*)&Bs[k][tc];
      float a[4] = {av.x, av.y, av.z, av.w};
      float b[4] = {bv.x, bv.y, bv.z, bv.w};
#pragma unroll
      for (int i = 0; i < 4; ++i)
#pragma unroll
        for (int j = 0; j < 4; ++j) acc[i][j] += a[i] * b[j];
    }
    __syncthreads();
  }
  float bias_v[4] = {0.f, 0.f, 0.f, 0.f};
  if (BIAS) {
    float4 bb = *(const float4*)(bias + bn + tc);
    bias_v[0] = bb.x; bias_v[1] = bb.y; bias_v[2] = bb.z; bias_v[3] = bb.w;
  }
#pragma unroll
  for (int i = 0; i < 4; ++i) {
    int r = bm + tr + i;
    if (r < M) {
      float4 o;
      o.x = acc[i][0] + bias_v[0];
      o.y = acc[i][1] + bias_v[1];
      o.z = acc[i][2] + bias_v[2];
      o.w = acc[i][3] + bias_v[3];
      if (RELU) {
        o.x = fmaxf(o.x, 0.f); o.y = fmaxf(o.y, 0.f);
        o.z = fmaxf(o.z, 0.f); o.w = fmaxf(o.w, 0.f);
      }
      *(float4*)&C[(size_t)r * N + bn + tc] = o;
    }
  }
}

// ---------------- GCN aggregation (gather, one wave/node, 256 feats, fp16 t) --------

template <typename OT>
__global__ __launch_bounds__(256) void k_agg(const _Float16* __restrict__ t,
                                             const int* __restrict__ row_ptr,
                                             const int* __restrict__ csr_src,
                                             const float* __restrict__ dinv,
                                             const float* __restrict__ bias,
                                             OT* __restrict__ out, int n_nodes) {
  int w = (int)((blockIdx.x * 256 + threadIdx.x) >> 6);
  int lane = threadIdx.x & 63;
  if (w >= n_nodes) return;
  float di = dinv[w];
  half4v v = *(const half4v*)(t + (size_t)w * 256 + lane * 4);
  float sw = di * di;
  float ax = (float)v[0] * sw, ay = (float)v[1] * sw, az = (float)v[2] * sw, aw = (float)v[3] * sw;
  int e0 = row_ptr[w], e1 = row_ptr[w + 1];
  for (int e = e0; e < e1; ++e) {
    int s = csr_src[e];
    float wgt = dinv[s] * di;
    half4v u = *(const half4v*)(t + (size_t)s * 256 + lane * 4);
    ax += (float)u[0] * wgt; ay += (float)u[1] * wgt;
    az += (float)u[2] * wgt; aw += (float)u[3] * wgt;
  }
  const float4 b = ((const float4*)bias)[lane];
  if constexpr (std::is_same_v<OT, float>) {
    float4 o;
    o.x = ax + b.x; o.y = ay + b.y; o.z = az + b.z; o.w = aw + b.w;
    ((float4*)(out + (size_t)w * 256))[lane] = o;
  } else {
    half4v o;
    o[0] = (_Float16)(ax + b.x); o[1] = (_Float16)(ay + b.y);
    o[2] = (_Float16)(az + b.z); o[3] = (_Float16)(aw + b.w);
    *(half4v*)(out + (size_t)w * 256 + lane * 4) = o;
  }
}

// ---------------- classifier: out[M,2] = h[M,K] @ Wc[K,2] + bc ----------------

__global__ __launch_bounds__(256) void k_cls(const float* __restrict__ h,
                                             const float* __restrict__ Wc,
                                             const float* __restrict__ bc,
                                             float* __restrict__ out, int M, int K) {
  __shared__ float w[512];
  for (int i = threadIdx.x; i < 2 * K; i += 256) w[i] = Wc[i];
  __syncthreads();
  int i = blockIdx.x * 256 + threadIdx.x;
  if (i >= M) return;
  float a0 = bc[0], a1 = bc[1];
  const float* hr = h + (size_t)i * K;
  for (int k = 0; k < K; ++k) {
    float a = hr[k];
    a0 += a * w[2 * k];
    a1 += a * w[2 * k + 1];
  }
  out[2 * i] = a0;
  out[2 * i + 1] = a1;
}

// ---------------- launch ----------------

extern "C" void kernel_launch(void* const* d_in, const int* in_sizes, int n_in,
                              void* d_out, int out_size, void* d_ws, size_t ws_size,
                              hipStream_t stream) {
  const float* x   = (const float*)d_in[0];
  const int*   ei  = (const int*)d_in[1];
  const float* W1  = (const float*)d_in[2];
  const float* b1  = (const float*)d_in[3];
  const float* Wg1 = (const float*)d_in[4];
  const float* bg1 = (const float*)d_in[5];
  const float* Wg2 = (const float*)d_in[6];
  const float* bg2 = (const float*)d_in[7];
  const float* W2  = (const float*)d_in[8];
  const float* b2  = (const float*)d_in[9];
  const float* Wc  = (const float*)d_in[10];
  const float* bc  = (const float*)d_in[11];
  float* out = (float*)d_out;

  const int hid     = in_sizes[3];            // 256
  const int in_dim  = in_sizes[2] / hid;      // 768
  const int out_dim = in_sizes[9];            // 128
  const int N       = in_sizes[0] / in_dim;   // 50000
  const int E       = in_sizes[1] / 2;        // 800000
  const int Batch   = out_size / 2;           // 1024

  const int* srcI = ei;
  const int* dstI = ei + E;

  char* ws = (char*)d_ws;
  size_t off = 0;
  auto alloc = [&](size_t bytes) -> void* {
    void* p = ws + off;
    off = (off + bytes + 255) & ~(size_t)255;
    return p;
  };
  _Float16* h0h  = (_Float16*)alloc((size_t)N * hid * 2);
  _Float16* t1h  = (_Float16*)alloc((size_t)N * hid * 2);
  _Float16* h1h  = (_Float16*)alloc((size_t)N * hid * 2);
  _Float16* t2h  = (_Float16*)alloc((size_t)N * hid * 2);
  _Float16* W1t  = (_Float16*)alloc((size_t)in_dim * hid * 2);
  _Float16* Wg1t = (_Float16*)alloc((size_t)hid * hid * 2);
  _Float16* Wg2t = (_Float16*)alloc((size_t)hid * hid * 2);
  float* agg2    = (float*)alloc((size_t)Batch * hid * 4);
  float* h3      = (float*)alloc((size_t)Batch * out_dim * 4);
  float* dinv    = (float*)alloc((size_t)N * 4);
  int*   cnt     = (int*)alloc((size_t)N * 4);
  int*   rowp    = (int*)alloc((size_t)(N + 1) * 4);
  int*   bsum    = (int*)alloc((size_t)1024 * 4);
  int*   cursor  = (int*)alloc((size_t)N * 4);
  int*   csrs    = (int*)alloc((size_t)E * 4);
  (void)ws_size; (void)n_in;

  dim3 blk(256);
  const int nb = (N + 1023) / 1024;

  // CSR + norm build
  k_zero_int<<<(N + 255) / 256, blk, 0, stream>>>(cnt, N);
  k_count<<<(E + 255) / 256, blk, 0, stream>>>(dstI, cnt, E);
  k_scan_local<<<nb, 1024, 0, stream>>>(cnt, rowp, bsum, N);
  k_scan_sums<<<1, 1024, 0, stream>>>(bsum, nb);
  k_finalize<<<(N + 255) / 256, blk, 0, stream>>>(rowp, bsum, cnt, cursor, dinv, N, E);
  k_fill<<<(E + 255) / 256, blk, 0, stream>>>(srcI, dstI, cursor, csrs, E);

  // fused weight convert + transpose (fp16)
  {
    int total = in_dim * hid + 2 * hid * hid;
    k_w_convert_all<<<(total + 255) / 256, blk, 0, stream>>>(W1, Wg1, Wg2, W1t, Wg1t, Wg2t, in_dim, hid);
  }

  dim3 gemm_grid(hid / 128, (N + 127) / 128);
  // h0 = relu(x @ W1 + b1)   (A fp32 -> converted in staging)
  k_gemm_mfma<float, 1, 1><<<gemm_grid, blk, 0, stream>>>(x, W1t, b1, h0h, N, hid, in_dim);
  // t1 = h0 @ Wg1
  k_gemm_mfma<_Float16, 0, 0><<<gemm_grid, blk, 0, stream>>>(h0h, Wg1t, nullptr, t1h, N, hid, hid);
  // h1 = aggregate(t1) + bg1  (fp16 out)
  k_agg<_Float16><<<(N + 3) / 4, blk, 0, stream>>>(t1h, rowp, csrs, dinv, bg1, h1h, N);
  // t2 = h1 @ Wg2
  k_gemm_mfma<_Float16, 0, 0><<<gemm_grid, blk, 0, stream>>>(h1h, Wg2t, nullptr, t2h, N, hid, hid);
  // conv2 aggregation only for rows [0, Batch)  (fp32 out)
  k_agg<float><<<(Batch + 3) / 4, blk, 0, stream>>>(t2h, rowp, csrs, dinv, bg2, agg2, Batch);
  // h3 = relu(agg2 @ W2 + b2)
  k_gemm<1, 1><<<dim3(out_dim / 64, (Batch + 63) / 64), blk, 0, stream>>>(agg2, W2, b2, h3, Batch, out_dim, hid);
  // logits = h3 @ Wc + bc
  k_cls<<<(Batch + 255) / 256, blk, 0, stream>>>(h3, Wc, bc, out, Batch, out_dim);
}

// Round 5
// 538.413 us; speedup vs baseline: 1.8093x; 1.0236x over previous
//
#include <hip/hip_runtime.h>
#include <hip/hip_bf16.h>
#include <cstdint>
#include <cstddef>
#include <type_traits>

typedef _Float16 half8 __attribute__((ext_vector_type(8)));
typedef _Float16 half4v __attribute__((ext_vector_type(4)));
typedef float float4v __attribute__((ext_vector_type(4)));

// ---------------- CSR build ----------------

__global__ void k_zero_int(int* __restrict__ p, int n) {
  int i = blockIdx.x * blockDim.x + threadIdx.x;
  if (i < n) p[i] = 0;
}

__global__ void k_count(const int* __restrict__ dst, int* __restrict__ cnt, int E) {
  int e = blockIdx.x * blockDim.x + threadIdx.x;
  if (e < E) atomicAdd(&cnt[dst[e]], 1);
}

// hierarchical exclusive scan: local (per-1024 block) -> sums -> fixup
__global__ __launch_bounds__(1024) void k_scan_local(const int* __restrict__ cnt,
                                                     int* __restrict__ rowp,
                                                     int* __restrict__ bsum, int n) {
  __shared__ int sm[1024];
  int tid = threadIdx.x;
  int i = blockIdx.x * 1024 + tid;
  int v = (i < n) ? cnt[i] : 0;
  sm[tid] = v;
  __syncthreads();
  for (int off = 1; off < 1024; off <<= 1) {
    int t = (tid >= off) ? sm[tid - off] : 0;
    __syncthreads();
    sm[tid] += t;
    __syncthreads();
  }
  if (i < n) rowp[i] = sm[tid] - v;  // exclusive (pre-fixup)
  if (tid == 1023) bsum[blockIdx.x] = sm[1023];
}

__global__ __launch_bounds__(1024) void k_scan_sums(int* __restrict__ bsum, int nb) {
  __shared__ int sm[1024];
  int tid = threadIdx.x;
  int v = (tid < nb) ? bsum[tid] : 0;
  sm[tid] = v;
  __syncthreads();
  for (int off = 1; off < 1024; off <<= 1) {
    int t = (tid >= off) ? sm[tid - off] : 0;
    __syncthreads();
    sm[tid] += t;
    __syncthreads();
  }
  if (tid < nb) bsum[tid] = sm[tid] - v;  // exclusive
}

// fixup + cursor copy + dinv, fused
__global__ void k_finalize(int* __restrict__ rowp, const int* __restrict__ bsum,
                           const int* __restrict__ cnt, int* __restrict__ cursor,
                           float* __restrict__ dinv, int n, int E) {
  int i = blockIdx.x * blockDim.x + threadIdx.x;
  if (i < n) {
    int v = rowp[i] + bsum[i >> 10];
    rowp[i] = v;
    cursor[i] = v;
    dinv[i] = rsqrtf((float)(cnt[i] + 1));  // +1 self loop
  }
  if (i == 0) rowp[n] = E;
}

__global__ void k_fill(const int* __restrict__ src, const int* __restrict__ dst,
                       int* __restrict__ cursor, int* __restrict__ csr_src, int E) {
  int e = blockIdx.x * blockDim.x + threadIdx.x;
  if (e < E) {
    int pos = atomicAdd(&cursor[dst[e]], 1);
    csr_src[pos] = src[e];
  }
}

// ---------------- fused weight convert+transpose (3 matrices in one launch) --------

__global__ void k_w_convert_all(const float* __restrict__ W1, const float* __restrict__ Wg1,
                                const float* __restrict__ Wg2, _Float16* __restrict__ W1t,
                                _Float16* __restrict__ Wg1t, _Float16* __restrict__ Wg2t,
                                int in_dim, int hid) {
  int idx = blockIdx.x * blockDim.x + threadIdx.x;
  int n1 = in_dim * hid;
  int n2 = hid * hid;
  if (idx < n1) {
    int n = idx / in_dim, k = idx - n * in_dim;
    W1t[idx] = (_Float16)W1[(size_t)k * hid + n];
  } else if (idx < n1 + n2) {
    int i2 = idx - n1;
    int n = i2 / hid, k = i2 - n * hid;
    Wg1t[i2] = (_Float16)Wg1[(size_t)k * hid + n];
  } else if (idx < n1 + 2 * n2) {
    int i2 = idx - n1 - n2;
    int n = i2 / hid, k = i2 - n * hid;
    Wg2t[i2] = (_Float16)Wg2[(size_t)k * hid + n];
  }
}

// ---------------- fp16 MFMA GEMM, 64x128 tile, dbuf + register prefetch ----------------
// out[M,N] = act(A[M,K] @ Bt^T [+ bias]) [* rowscale[r]]; Bt fp16 [N,K].
// 256 threads = 4 waves (2x2), each wave 32x64 (acc 2x4), 8 MFMA/k-step.
// Small tile -> 1564 blocks for M=50000 -> ~5-6 blocks/CU: TLP hides HBM latency.
// NOTE: no device lambdas (clang-22 frontend crash in round 3).

#define LDSS 40  // LDS row stride in halves (32 + 8 pad -> <=2-way banks, free)

template <typename AT>
__device__ __forceinline__ half8 load_row_h8(const AT* __restrict__ p, bool ok) {
  half8 v = {};
  if (ok) {
    if constexpr (std::is_same_v<AT, float>) {
      float4 f0 = *(const float4*)p;
      float4 f1 = *(const float4*)(p + 4);
      v[0] = (_Float16)f0.x; v[1] = (_Float16)f0.y;
      v[2] = (_Float16)f0.z; v[3] = (_Float16)f0.w;
      v[4] = (_Float16)f1.x; v[5] = (_Float16)f1.y;
      v[6] = (_Float16)f1.z; v[7] = (_Float16)f1.w;
    } else {
      v = *(const half8*)p;
    }
  }
  return v;
}

template <typename AT, int RELU, int BIAS, int SCALE>
__global__ __launch_bounds__(256, 4) void k_gemm_mfma(const AT* __restrict__ A,
                                                      const _Float16* __restrict__ Bt,
                                                      const float* __restrict__ bias,
                                                      const float* __restrict__ rowscale,
                                                      _Float16* __restrict__ out,
                                                      int M, int N, int K) {
  __shared__ _Float16 Asm[2][64 * LDSS];
  __shared__ _Float16 Bsm[2][128 * LDSS];
  const int tid = threadIdx.x;
  const int bm = blockIdx.y * 64;
  const int bn = blockIdx.x * 128;
  const int wave = tid >> 6;
  const int wm = (wave >> 1) * 32;   // 0 or 32
  const int wn = (wave & 1) * 64;    // 0 or 64
  const int quad = (tid & 63) >> 4;
  const int l15 = tid & 15;

  // staging assignments
  const int ar = tid >> 2;           // 0..63  A row
  const int ac = (tid & 3) * 8;      // A chunk (halves)
  const int br0 = tid >> 1;          // B linear chunks: idx = tid, tid+256
  // B chunk p: idx = tid + p*256; r = idx>>2, c = (idx&3)*8

  const int gra = bm + ar;
  const bool oka = gra < M;
  const AT* Apt = A + (size_t)gra * K + ac;
  const int br_0 = tid >> 2, bc_0 = (tid & 3) * 8;
  const int br_1 = (tid + 256) >> 2, bc_1 = ((tid + 256) & 3) * 8;
  const _Float16* Bp0 = Bt + (size_t)(bn + br_0) * K + bc_0;
  const _Float16* Bp1 = Bt + (size_t)(bn + br_1) * K + bc_1;

  _Float16* AsW = &Asm[0][0] + ar * LDSS + ac;
  _Float16* BsW0 = &Bsm[0][0] + br_0 * LDSS + bc_0;
  _Float16* BsW1 = &Bsm[0][0] + br_1 * LDSS + bc_1;
  const int abufstep = 64 * LDSS;
  const int bbufstep = 128 * LDSS;
  (void)br0;

  float4v acc[2][4];
#pragma unroll
  for (int i = 0; i < 2; ++i)
#pragma unroll
    for (int j = 0; j < 4; ++j) acc[i][j] = (float4v){0.f, 0.f, 0.f, 0.f};

  // prologue: tile 0 -> buffer 0
  half8 pa = load_row_h8<AT>(Apt, oka);
  half8 pb0 = *(const half8*)Bp0;
  half8 pb1 = *(const half8*)Bp1;
  *(half8*)AsW = pa;
  *(half8*)BsW0 = pb0;
  *(half8*)BsW1 = pb1;

  const int nk = K >> 5;
  int buf = 0;
  for (int kt = 0; kt < nk; ++kt) {
    __syncthreads();
    if (kt + 1 < nk) {
      int k0 = (kt + 1) << 5;
      pa = load_row_h8<AT>(Apt + k0, oka);
      pb0 = *(const half8*)(Bp0 + k0);
      pb1 = *(const half8*)(Bp1 + k0);
    }
    const _Float16* Ab = &Asm[0][0] + buf * abufstep;
    const _Float16* Bb = &Bsm[0][0] + buf * bbufstep;
    half8 af[2], bf[4];
#pragma unroll
    for (int i = 0; i < 2; ++i)
      af[i] = *(const half8*)(Ab + (wm + i * 16 + l15) * LDSS + quad * 8);
#pragma unroll
    for (int j = 0; j < 4; ++j)
      bf[j] = *(const half8*)(Bb + (wn + j * 16 + l15) * LDSS + quad * 8);
#pragma unroll
    for (int i = 0; i < 2; ++i)
#pragma unroll
      for (int j = 0; j < 4; ++j)
        acc[i][j] = __builtin_amdgcn_mfma_f32_16x16x32_f16(af[i], bf[j], acc[i][j], 0, 0, 0);
    if (kt + 1 < nk) {
      int nbuf = buf ^ 1;
      *(half8*)(AsW + nbuf * abufstep) = pa;
      *(half8*)(BsW0 + nbuf * bbufstep) = pb0;
      *(half8*)(BsW1 + nbuf * bbufstep) = pb1;
    }
    buf ^= 1;
  }

  // epilogue: C/D layout col=lane&15, row=quad*4+reg
#pragma unroll
  for (int j = 0; j < 4; ++j) {
    int c = bn + wn + j * 16 + l15;
    float bv = BIAS ? bias[c] : 0.f;
#pragma unroll
    for (int i = 0; i < 2; ++i) {
      int rbase = bm + wm + i * 16 + quad * 4;
      float4v a = acc[i][j];
#pragma unroll
      for (int reg = 0; reg < 4; ++reg) {
        int r = rbase + reg;
        if (r < M) {
          float v = a[reg] + bv;
          if (RELU) v = fmaxf(v, 0.f);
          if (SCALE) v *= rowscale[r];
          out[(size_t)r * N + c] = (_Float16)v;
        }
      }
    }
  }
}

// ---------------- fp32 tiled GEMM (tail): C = act(A @ B + bias) ----------------

template <int RELU, int BIAS>
__global__ __launch_bounds__(256) void k_gemm(const float* __restrict__ A,
                                              const float* __restrict__ B,
                                              const float* __restrict__ bias,
                                              float* __restrict__ C,
                                              int M, int N, int K) {
  __shared__ float As[16][68];
  __shared__ float Bs[16][68];
  const int bm = blockIdx.y * 64;
  const int bn = blockIdx.x * 64;
  const int tid = threadIdx.x;
  const int tr = (tid >> 4) << 2;
  const int tc = (tid & 15) << 2;
  const int lm  = tid >> 2;
  const int lk  = (tid & 3) << 2;
  const int lk2 = tid >> 4;
  const int ln  = (tid & 15) << 2;
  const bool arow_ok = (bm + lm) < M;
  const float* Aptr = A + (size_t)(bm + lm) * K + lk;
  const float* Bptr = B + (size_t)lk2 * N + bn + ln;
  float acc[4][4] = {};
  for (int k0 = 0; k0 < K; k0 += 16) {
    float4 a4 = make_float4(0.f, 0.f, 0.f, 0.f);
    if (arow_ok) a4 = *(const float4*)(Aptr + k0);
    float4 b4 = *(const float4*)(Bptr + (size_t)k0 * N);
    As[lk + 0][lm] = a4.x;
    As[lk + 1][lm] = a4.y;
    As[lk + 2][lm] = a4.z;
    As[lk + 3][lm] = a4.w;
    *(float4*)&Bs[lk2][ln] = b4;
    __syncthreads();
#pragma unroll
    for (int k = 0; k < 16; ++k) {
      float4 av = *(const float4*)&As[k][tr];
      float4 bv = *(const float4*)&Bs[k][tc];
      float a[4] = {av.x, av.y, av.z, av.w};
      float b[4] = {bv.x, bv.y, bv.z, bv.w};
#pragma unroll
      for (int i = 0; i < 4; ++i)
#pragma unroll
        for (int j = 0; j < 4; ++j) acc[i][j] += a[i] * b[j];
    }
    __syncthreads();
  }
  float bias_v[4] = {0.f, 0.f, 0.f, 0.f};
  if (BIAS) {
    float4 bb = *(const float4*)(bias + bn + tc);
    bias_v[0] = bb.x; bias_v[1] = bb.y; bias_v[2] = bb.z; bias_v[3] = bb.w;
  }
#pragma unroll
  for (int i = 0; i < 4; ++i) {
    int r = bm + tr + i;
    if (r < M) {
      float4 o;
      o.x = acc[i][0] + bias_v[0];
      o.y = acc[i][1] + bias_v[1];
      o.z = acc[i][2] + bias_v[2];
      o.w = acc[i][3] + bias_v[3];
      if (RELU) {
        o.x = fmaxf(o.x, 0.f); o.y = fmaxf(o.y, 0.f);
        o.z = fmaxf(o.z, 0.f); o.w = fmaxf(o.w, 0.f);
      }
      *(float4*)&C[(size_t)r * N + bn + tc] = o;
    }
  }
}

// ---------------- GCN aggregation (gather, one wave/node, 256 feats) ----------------
// t is PRE-SCALED: t'[i] = t[i]*dinv[i].  out[i] = (t'[i] + sum t'[src]) * dinv[i] + b

template <typename OT>
__global__ __launch_bounds__(256) void k_agg(const _Float16* __restrict__ t,
                                             const int* __restrict__ row_ptr,
                                             const int* __restrict__ csr_src,
                                             const float* __restrict__ dinv,
                                             const float* __restrict__ bias,
                                             OT* __restrict__ out, int n_nodes) {
  int w = (int)((blockIdx.x * 256 + threadIdx.x) >> 6);
  int lane = threadIdx.x & 63;
  if (w >= n_nodes) return;
  float di = dinv[w];
  half4v v = *(const half4v*)(t + (size_t)w * 256 + lane * 4);
  float ax = (float)v[0], ay = (float)v[1], az = (float)v[2], aw = (float)v[3];
  int e0 = row_ptr[w], e1 = row_ptr[w + 1];
  int e = e0;
  for (; e + 4 <= e1; e += 4) {
    int s0 = csr_src[e];
    int s1 = csr_src[e + 1];
    int s2 = csr_src[e + 2];
    int s3 = csr_src[e + 3];
    half4v u0 = *(const half4v*)(t + (size_t)s0 * 256 + lane * 4);
    half4v u1 = *(const half4v*)(t + (size_t)s1 * 256 + lane * 4);
    half4v u2 = *(const half4v*)(t + (size_t)s2 * 256 + lane * 4);
    half4v u3 = *(const half4v*)(t + (size_t)s3 * 256 + lane * 4);
    ax += (float)u0[0] + (float)u1[0] + (float)u2[0] + (float)u3[0];
    ay += (float)u0[1] + (float)u1[1] + (float)u2[1] + (float)u3[1];
    az += (float)u0[2] + (float)u1[2] + (float)u2[2] + (float)u3[2];
    aw += (float)u0[3] + (float)u1[3] + (float)u2[3] + (float)u3[3];
  }
  for (; e < e1; ++e) {
    int s = csr_src[e];
    half4v u = *(const half4v*)(t + (size_t)s * 256 + lane * 4);
    ax += (float)u[0]; ay += (float)u[1]; az += (float)u[2]; aw += (float)u[3];
  }
  const float4 b = ((const float4*)bias)[lane];
  if constexpr (std::is_same_v<OT, float>) {
    float4 o;
    o.x = ax * di + b.x; o.y = ay * di + b.y;
    o.z = az * di + b.z; o.w = aw * di + b.w;
    ((float4*)(out + (size_t)w * 256))[lane] = o;
  } else {
    half4v o;
    o[0] = (_Float16)(ax * di + b.x); o[1] = (_Float16)(ay * di + b.y);
    o[2] = (_Float16)(az * di + b.z); o[3] = (_Float16)(aw * di + b.w);
    *(half4v*)(out + (size_t)w * 256 + lane * 4) = o;
  }
}

// ---------------- classifier: out[M,2] = h[M,K] @ Wc[K,2] + bc ----------------

__global__ __launch_bounds__(256) void k_cls(const float* __restrict__ h,
                                             const float* __restrict__ Wc,
                                             const float* __restrict__ bc,
                                             float* __restrict__ out, int M, int K) {
  __shared__ float w[512];
  for (int i = threadIdx.x; i < 2 * K; i += 256) w[i] = Wc[i];
  __syncthreads();
  int i = blockIdx.x * 256 + threadIdx.x;
  if (i >= M) return;
  float a0 = bc[0], a1 = bc[1];
  const float* hr = h + (size_t)i * K;
  for (int k = 0; k < K; ++k) {
    float a = hr[k];
    a0 += a * w[2 * k];
    a1 += a * w[2 * k + 1];
  }
  out[2 * i] = a0;
  out[2 * i + 1] = a1;
}

// ---------------- launch ----------------

extern "C" void kernel_launch(void* const* d_in, const int* in_sizes, int n_in,
                              void* d_out, int out_size, void* d_ws, size_t ws_size,
                              hipStream_t stream) {
  const float* x   = (const float*)d_in[0];
  const int*   ei  = (const int*)d_in[1];
  const float* W1  = (const float*)d_in[2];
  const float* b1  = (const float*)d_in[3];
  const float* Wg1 = (const float*)d_in[4];
  const float* bg1 = (const float*)d_in[5];
  const float* Wg2 = (const float*)d_in[6];
  const float* bg2 = (const float*)d_in[7];
  const float* W2  = (const float*)d_in[8];
  const float* b2  = (const float*)d_in[9];
  const float* Wc  = (const float*)d_in[10];
  const float* bc  = (const float*)d_in[11];
  float* out = (float*)d_out;

  const int hid     = in_sizes[3];            // 256
  const int in_dim  = in_sizes[2] / hid;      // 768
  const int out_dim = in_sizes[9];            // 128
  const int N       = in_sizes[0] / in_dim;   // 50000
  const int E       = in_sizes[1] / 2;        // 800000
  const int Batch   = out_size / 2;           // 1024

  const int* srcI = ei;
  const int* dstI = ei + E;

  char* ws = (char*)d_ws;
  size_t off = 0;
  auto alloc = [&](size_t bytes) -> void* {
    void* p = ws + off;
    off = (off + bytes + 255) & ~(size_t)255;
    return p;
  };
  _Float16* h0h  = (_Float16*)alloc((size_t)N * hid * 2);
  _Float16* t1h  = (_Float16*)alloc((size_t)N * hid * 2);   // pre-scaled by dinv
  _Float16* h1h  = (_Float16*)alloc((size_t)N * hid * 2);
  _Float16* t2h  = (_Float16*)alloc((size_t)N * hid * 2);   // pre-scaled by dinv
  _Float16* W1t  = (_Float16*)alloc((size_t)in_dim * hid * 2);
  _Float16* Wg1t = (_Float16*)alloc((size_t)hid * hid * 2);
  _Float16* Wg2t = (_Float16*)alloc((size_t)hid * hid * 2);
  float* agg2    = (float*)alloc((size_t)Batch * hid * 4);
  float* h3      = (float*)alloc((size_t)Batch * out_dim * 4);
  float* dinv    = (float*)alloc((size_t)N * 4);
  int*   cnt     = (int*)alloc((size_t)N * 4);
  int*   rowp    = (int*)alloc((size_t)(N + 1) * 4);
  int*   bsum    = (int*)alloc((size_t)1024 * 4);
  int*   cursor  = (int*)alloc((size_t)N * 4);
  int*   csrs    = (int*)alloc((size_t)E * 4);
  (void)ws_size; (void)n_in;

  dim3 blk(256);
  const int nb = (N + 1023) / 1024;

  // CSR + norm build
  k_zero_int<<<(N + 255) / 256, blk, 0, stream>>>(cnt, N);
  k_count<<<(E + 255) / 256, blk, 0, stream>>>(dstI, cnt, E);
  k_scan_local<<<nb, 1024, 0, stream>>>(cnt, rowp, bsum, N);
  k_scan_sums<<<1, 1024, 0, stream>>>(bsum, nb);
  k_finalize<<<(N + 255) / 256, blk, 0, stream>>>(rowp, bsum, cnt, cursor, dinv, N, E);
  k_fill<<<(E + 255) / 256, blk, 0, stream>>>(srcI, dstI, cursor, csrs, E);

  // fused weight convert + transpose (fp16)
  {
    int total = in_dim * hid + 2 * hid * hid;
    k_w_convert_all<<<(total + 255) / 256, blk, 0, stream>>>(W1, Wg1, Wg2, W1t, Wg1t, Wg2t, in_dim, hid);
  }

  dim3 gemm_grid(hid / 128, (N + 63) / 64);
  // h0 = relu(x @ W1 + b1)
  k_gemm_mfma<float, 1, 1, 0><<<gemm_grid, blk, 0, stream>>>(x, W1t, b1, nullptr, h0h, N, hid, in_dim);
  // t1' = (h0 @ Wg1) * dinv[row]
  k_gemm_mfma<_Float16, 0, 0, 1><<<gemm_grid, blk, 0, stream>>>(h0h, Wg1t, nullptr, dinv, t1h, N, hid, hid);
  // h1 = (t1'[i] + sum t1'[src]) * dinv[i] + bg1   (fp16 out)
  k_agg<_Float16><<<(N + 3) / 4, blk, 0, stream>>>(t1h, rowp, csrs, dinv, bg1, h1h, N);
  // t2' = (h1 @ Wg2) * dinv[row]
  k_gemm_mfma<_Float16, 0, 0, 1><<<gemm_grid, blk, 0, stream>>>(h1h, Wg2t, nullptr, dinv, t2h, N, hid, hid);
  // conv2 aggregation only for rows [0, Batch)  (fp32 out)
  k_agg<float><<<(Batch + 3) / 4, blk, 0, stream>>>(t2h, rowp, csrs, dinv, bg2, agg2, Batch);
  // h3 = relu(agg2 @ W2 + b2)
  k_gemm<1, 1><<<dim3(out_dim / 64, (Batch + 63) / 64), blk, 0, stream>>>(agg2, W2, b2, h3, Batch, out_dim, hid);
  // logits = h3 @ Wc + bc
  k_cls<<<(Batch + 255) / 256, blk, 0, stream>>>(h3, Wc, bc, out, Batch, out_dim);
}